// Round 1
// baseline (5472.510 us; speedup 1.0000x reference)
//
#include <hip/hip_runtime.h>
#include <cstdint>
#include <cstddef>

#define SEQ 5000
#define CIN 12
#define KL 9
#define ND 10
#define KPD 1000
#define NB 16
#define TAPS (CIN * KL)  // 108

__device__ __forceinline__ unsigned fkey(float f) {
    unsigned u = __float_as_uint(f);
    return (u & 0x80000000u) ? ~u : (u | 0x80000000u);
}
__device__ __forceinline__ float unfkey(unsigned k) {
    unsigned u = (k & 0x80000000u) ? (k ^ 0x80000000u) : ~k;
    return __uint_as_float(u);
}

// grid: (t-chunks=20, ND, NB), block 256
__global__ __launch_bounds__(256) void mr_main(
    const float* __restrict__ x, const float* __restrict__ w,
    const float* __restrict__ bias, unsigned* __restrict__ gkey,
    unsigned* __restrict__ gcnt)
{
    const int tid = threadIdx.x;
    const int tb  = blockIdx.x;
    const int di  = blockIdx.y;
    const int b   = blockIdx.z;
    const int d   = 1 << di;
    const int t   = tb * 256 + tid;
    const bool valid = t < SEQ;

    __shared__ unsigned s_key[KPD];
    __shared__ unsigned s_cnt[KPD];
    for (int k = tid; k < KPD; k += 256) { s_key[k] = 0u; s_cnt[k] = 0u; }
    __syncthreads();

    // gather per-thread patch into registers (SAME padding: pad_lo = 4d)
    float patch[TAPS];
    const float* xb = x + (size_t)b * CIN * SEQ;
    const int base = t - 4 * d;
#pragma unroll
    for (int c = 0; c < CIN; ++c) {
#pragma unroll
        for (int j = 0; j < KL; ++j) {
            const int idx = base + j * d;
            float v = 0.f;
            if (valid && idx >= 0 && idx < SEQ) v = xb[c * SEQ + idx];
            patch[c * KL + j] = v;
        }
    }

    const float* wb = w + (size_t)di * KPD * TAPS;  // [KPD][108], block-uniform
    const float* bb = bias + (size_t)di * KPD;
    const int lane = tid & 63;

    for (int k = 0; k < KPD; ++k) {
        const float* wk = wb + (size_t)k * TAPS;   // uniform address -> s_load
        float a0 = 0.f, a1 = 0.f, a2 = 0.f, a3 = 0.f;
#pragma unroll
        for (int r = 0; r < TAPS; r += 4) {
            a0 = fmaf(wk[r + 0], patch[r + 0], a0);
            a1 = fmaf(wk[r + 1], patch[r + 1], a1);
            a2 = fmaf(wk[r + 2], patch[r + 2], a2);
            a3 = fmaf(wk[r + 3], patch[r + 3], a3);
        }
        const float acc = (a0 + a1) + (a2 + a3);

        float m = valid ? acc : -__builtin_inff();
#pragma unroll
        for (int off = 32; off >= 1; off >>= 1)
            m = fmaxf(m, __shfl_xor(m, off, 64));
        const unsigned long long ball = __ballot(valid && (acc > bb[k]));
        if (lane == 0) {
            atomicMax(&s_key[k], fkey(m));
            atomicAdd(&s_cnt[k], (unsigned)__popcll(ball));
        }
    }
    __syncthreads();

    const size_t slotbase = ((size_t)b * ND + di) * KPD;
    for (int k = tid; k < KPD; k += 256) {
        atomicMax(&gkey[slotbase + k], s_key[k]);
        atomicAdd(&gcnt[slotbase + k], s_cnt[k]);
    }
}

__global__ __launch_bounds__(256) void mr_fin(
    const unsigned* __restrict__ gkey, const unsigned* __restrict__ gcnt,
    float* __restrict__ out)
{
    const int i = blockIdx.x * 256 + threadIdx.x;  // over NB*ND*KPD
    if (i >= NB * ND * KPD) return;
    const int k  = i % KPD;
    const int di = (i / KPD) % ND;
    const int b  = i / (KPD * ND);
    const float maxv = unfkey(gkey[i]);
    const float ppv  = (float)gcnt[i] * (1.0f / (float)SEQ);
    float* ob = out + (size_t)b * (2 * ND * KPD);
    ob[di * 2 * KPD + k]       = maxv;
    ob[di * 2 * KPD + KPD + k] = ppv;
}

extern "C" void kernel_launch(void* const* d_in, const int* in_sizes, int n_in,
                              void* d_out, int out_size, void* d_ws, size_t ws_size,
                              hipStream_t stream) {
    const float* x    = (const float*)d_in[0];
    const float* w    = (const float*)d_in[1];
    const float* bias = (const float*)d_in[2];
    float* out = (float*)d_out;

    unsigned* gkey = (unsigned*)d_ws;
    unsigned* gcnt = gkey + (size_t)NB * ND * KPD;

    hipMemsetAsync(d_ws, 0, (size_t)NB * ND * KPD * 2 * sizeof(unsigned), stream);

    dim3 grid((SEQ + 255) / 256, ND, NB);
    mr_main<<<grid, 256, 0, stream>>>(x, w, bias, gkey, gcnt);

    const int tot = NB * ND * KPD;
    mr_fin<<<(tot + 255) / 256, 256, 0, stream>>>(gkey, gcnt, out);
}

// Round 2
// 469.536 us; speedup vs baseline: 11.6551x; 11.6551x over previous
//
#include <hip/hip_runtime.h>
#include <cstdint>
#include <cstddef>

#define SEQ 5000
#define CIN 12
#define KL 9
#define ND 10
#define KPD 1000
#define NB 16
#define KPAD 128          // padded taps (108 -> 128)
#define NKP 1024          // padded kernels per dilation (1000 -> 1024)
#define BM 64             // t-points per block
#define NTILES 16         // NKP / 64

typedef __attribute__((ext_vector_type(4))) float f32x4;
typedef __attribute__((ext_vector_type(8))) __bf16 bf16x8;
typedef __attribute__((ext_vector_type(8))) unsigned short u16x8;

__device__ __forceinline__ unsigned fkey(float f) {
    unsigned u = __float_as_uint(f);
    return (u & 0x80000000u) ? ~u : (u | 0x80000000u);
}
__device__ __forceinline__ float unfkey(unsigned k) {
    unsigned u = (k & 0x80000000u) ? (k ^ 0x80000000u) : ~k;
    return __uint_as_float(u);
}
__device__ __forceinline__ unsigned short f2bf(float f) {
    unsigned u = __float_as_uint(f);
    u += 0x7fffu + ((u >> 16) & 1u);
    return (unsigned short)(u >> 16);
}

// ---- weight prep: [10][1000][108] f32 -> [10][1024][128] bf16, zero-padded ----
__global__ __launch_bounds__(256) void wprep(const float* __restrict__ w,
                                             unsigned short* __restrict__ wbf) {
    const int i = blockIdx.x * 256 + threadIdx.x;   // over ND*NKP*KPAD
    if (i >= ND * NKP * KPAD) return;
    const int kk   = i & (KPAD - 1);
    const int krow = (i >> 7) & (NKP - 1);
    const int di   = i >> 17;
    float v = 0.f;
    if (krow < KPD && kk < CIN * KL)
        v = w[((size_t)di * KPD + krow) * (CIN * KL) + kk];
    wbf[i] = f2bf(v);
}

template <bool TAIL>
__device__ __forceinline__ void mr_body(
    const float* __restrict__ xb, const unsigned short* __restrict__ wd,
    const float* __restrict__ bb, unsigned* __restrict__ gkey,
    unsigned* __restrict__ gcnt, int d, int t0,
    unsigned short* lA, unsigned* s_key, unsigned* s_cnt, size_t slotbase)
{
    const int tid  = threadIdx.x;
    const int lane = tid & 63;
    const int wv   = tid >> 6;

    for (int k2 = tid; k2 < NKP; k2 += 256) { s_key[k2] = 0u; s_cnt[k2] = 0u; }

    // ---- gather patch A[64][128] into swizzled LDS (lane = t -> coalesced x reads) ----
    {
        const int row  = tid & 63;
        const int cw   = tid >> 6;           // col group: 32 taps each
        const int base = t0 + row - 4 * d;   // SAME padding: pad_lo = 4d
        int cc = cw * 32;
        int c = cc / 9, j = cc - c * 9;
#pragma unroll
        for (int m = 0; m < 4; ++m) {
            u16x8 pk;
#pragma unroll
            for (int e = 0; e < 8; ++e) {
                const int idx = base + j * d;
                float v = 0.f;
                if ((cc < CIN * KL) && idx >= 0 && idx < SEQ) v = xb[c * SEQ + idx];
                pk[e] = f2bf(v);
                ++cc;
                if (++j == KL) { j = 0; ++c; }
            }
            const int cb   = cw * 64 + m * 16;
            const int addr = row * 256 + (cb ^ ((row & 7) << 4));
            *(u16x8*)((char*)lA + addr) = pk;
        }
    }
    __syncthreads();

    // ---- A fragments -> registers (16x ds_read_b128, swizzled: 2-way max = free) ----
    const int fr = lane & 15;   // frag row (t within 16) / frag col (k within 16)
    const int ks = lane >> 4;   // k-slice group
    bf16x8 afrag[4][4];
#pragma unroll
    for (int m = 0; m < 4; ++m) {
        const int row = m * 16 + fr;
#pragma unroll
        for (int kk = 0; kk < 4; ++kk) {
            const int cb   = kk * 64 + ks * 16;
            const int addr = row * 256 + (cb ^ ((row & 7) << 4));
            afrag[m][kk] = *(const bf16x8*)((const char*)lA + addr);
        }
    }

    // ---- k-tile loop: B-frags straight from global (L2-resident), no barriers ----
    for (int kt = 0; kt < NTILES; ++kt) {
        const int kcol = kt * 64 + wv * 16 + fr;     // padded kernel index
        const unsigned short* wr = wd + (size_t)kcol * KPAD + ks * 8;
        bf16x8 bfrag[4];
#pragma unroll
        for (int kk = 0; kk < 4; ++kk)
            bfrag[kk] = *(const bf16x8*)(wr + kk * 32);

        f32x4 acc[4];
#pragma unroll
        for (int m = 0; m < 4; ++m) acc[m] = (f32x4){0.f, 0.f, 0.f, 0.f};
#pragma unroll
        for (int m = 0; m < 4; ++m)
#pragma unroll
            for (int kk = 0; kk < 4; ++kk)
                acc[m] = __builtin_amdgcn_mfma_f32_16x16x32_bf16(
                    afrag[m][kk], bfrag[kk], acc[m], 0, 0, 0);

        const float bv = (kcol < KPD) ? bb[kcol] : 3.0e38f;
        float pmax = -3.0e38f;
        unsigned pcnt = 0;
#pragma unroll
        for (int m = 0; m < 4; ++m) {
#pragma unroll
            for (int r = 0; r < 4; ++r) {
                const float v = acc[m][r];
                if (TAIL) {
                    const bool ok = (t0 + m * 16 + ks * 4 + r) < SEQ;
                    pmax = fmaxf(pmax, ok ? v : -3.0e38f);
                    pcnt += (ok && (v > bv)) ? 1u : 0u;
                } else {
                    pmax = fmaxf(pmax, v);
                    pcnt += (v > bv) ? 1u : 0u;
                }
            }
        }
        pmax = fmaxf(pmax, __shfl_xor(pmax, 16, 64));
        pcnt += (unsigned)__shfl_xor((int)pcnt, 16, 64);
        pmax = fmaxf(pmax, __shfl_xor(pmax, 32, 64));
        pcnt += (unsigned)__shfl_xor((int)pcnt, 32, 64);
        if (ks == 0) {
            atomicMax(&s_key[kcol], fkey(pmax));
            atomicAdd(&s_cnt[kcol], pcnt);
        }
    }
    __syncthreads();

    for (int k2 = tid; k2 < NKP; k2 += 256) {
        if (k2 < KPD) {
            atomicMax(&gkey[slotbase + k2], s_key[k2]);
            atomicAdd(&gcnt[slotbase + k2], s_cnt[k2]);
        }
    }
}

// grid: (79 t-chunks, ND, NB), block 256
__global__ __launch_bounds__(256) void mr_main(
    const float* __restrict__ x, const unsigned short* __restrict__ wbf,
    const float* __restrict__ bias, unsigned* __restrict__ gkey,
    unsigned* __restrict__ gcnt)
{
    const int tb = blockIdx.x;
    const int di = blockIdx.y;
    const int b  = blockIdx.z;
    const int d  = 1 << di;
    const int t0 = tb * BM;

    __shared__ __align__(16) unsigned short lA[BM * KPAD];
    __shared__ unsigned s_key[NKP];
    __shared__ unsigned s_cnt[NKP];

    const float* xb = x + (size_t)b * CIN * SEQ;
    const unsigned short* wd = wbf + (size_t)di * NKP * KPAD;
    const float* bb = bias + (size_t)di * KPD;
    const size_t slotbase = ((size_t)b * ND + di) * KPD;

    if (t0 + BM <= SEQ)
        mr_body<false>(xb, wd, bb, gkey, gcnt, d, t0, lA, s_key, s_cnt, slotbase);
    else
        mr_body<true>(xb, wd, bb, gkey, gcnt, d, t0, lA, s_key, s_cnt, slotbase);
}

__global__ __launch_bounds__(256) void mr_fin(
    const unsigned* __restrict__ gkey, const unsigned* __restrict__ gcnt,
    float* __restrict__ out)
{
    const int i = blockIdx.x * 256 + threadIdx.x;   // over NB*ND*KPD
    if (i >= NB * ND * KPD) return;
    const int k  = i % KPD;
    const int di = (i / KPD) % ND;
    const int b  = i / (KPD * ND);
    const float maxv = unfkey(gkey[i]);
    const float ppv  = (float)gcnt[i] * (1.0f / (float)SEQ);
    float* ob = out + (size_t)b * (2 * ND * KPD);
    ob[di * 2 * KPD + k]       = maxv;
    ob[di * 2 * KPD + KPD + k] = ppv;
}

extern "C" void kernel_launch(void* const* d_in, const int* in_sizes, int n_in,
                              void* d_out, int out_size, void* d_ws, size_t ws_size,
                              hipStream_t stream) {
    const float* x    = (const float*)d_in[0];
    const float* w    = (const float*)d_in[1];
    const float* bias = (const float*)d_in[2];
    float* out = (float*)d_out;

    unsigned* gkey = (unsigned*)d_ws;
    unsigned* gcnt = gkey + (size_t)NB * ND * KPD;
    unsigned short* wbf = (unsigned short*)(gcnt + (size_t)NB * ND * KPD);

    hipMemsetAsync(d_ws, 0, (size_t)NB * ND * KPD * 2 * sizeof(unsigned), stream);

    const int wtot = ND * NKP * KPAD;
    wprep<<<(wtot + 255) / 256, 256, 0, stream>>>(w, wbf);

    dim3 grid((SEQ + BM - 1) / BM, ND, NB);
    mr_main<<<grid, 256, 0, stream>>>(x, wbf, bias, gkey, gcnt);

    const int tot = NB * ND * KPD;
    mr_fin<<<(tot + 255) / 256, 256, 0, stream>>>(gkey, gcnt, out);
}

// Round 5
// 469.327 us; speedup vs baseline: 11.6603x; 1.0004x over previous
//
#include <hip/hip_runtime.h>
#include <cstdint>
#include <cstddef>

#define SEQ 5000
#define CIN 12
#define KL 9
#define ND 10
#define KPD 1000
#define NB 16
#define KPAD 128          // padded taps (108 -> 128)
#define NKP 1024          // padded kernels per dilation (1000 -> 1024)
#define BM 64             // t-points per block
#define NTILES 16         // NKP / 64

typedef __attribute__((ext_vector_type(4))) float f32x4;
typedef __attribute__((ext_vector_type(8))) __bf16 bf16x8;
typedef __attribute__((ext_vector_type(8))) unsigned short u16x8;

__device__ __forceinline__ unsigned fkey(float f) {
    unsigned u = __float_as_uint(f);
    return (u & 0x80000000u) ? ~u : (u | 0x80000000u);
}
__device__ __forceinline__ float unfkey(unsigned k) {
    unsigned u = (k & 0x80000000u) ? (k ^ 0x80000000u) : ~k;
    return __uint_as_float(u);
}
__device__ __forceinline__ unsigned short f2bf(float f) {
    unsigned u = __float_as_uint(f);
    u += 0x7fffu + ((u >> 16) & 1u);
    return (unsigned short)(u >> 16);
}

// ---- weight prep: [10][1000][108] f32 -> [10][1024][128] bf16, zero-padded ----
__global__ __launch_bounds__(256) void wprep(const float* __restrict__ w,
                                             unsigned short* __restrict__ wbf) {
    const int i = blockIdx.x * 256 + threadIdx.x;   // over ND*NKP*KPAD
    if (i >= ND * NKP * KPAD) return;
    const int kk   = i & (KPAD - 1);
    const int krow = (i >> 7) & (NKP - 1);
    const int di   = i >> 17;
    float v = 0.f;
    if (krow < KPD && kk < CIN * KL)
        v = w[((size_t)di * KPD + krow) * (CIN * KL) + kk];
    wbf[i] = f2bf(v);
}

template <bool TAIL>
__device__ __forceinline__ void mr_body(
    const float* __restrict__ xb, const unsigned short* __restrict__ wd,
    const float* __restrict__ bb, unsigned* __restrict__ gkey,
    unsigned* __restrict__ gcnt, int d, int t0,
    unsigned short* lA, size_t slotbase)
{
    const int tid  = threadIdx.x;
    const int lane = tid & 63;
    const int wv   = tid >> 6;

    // ---- gather patch A[64][128] into swizzled LDS (lane = t -> coalesced x reads) ----
    {
        const int row  = tid & 63;
        const int cw   = tid >> 6;           // col group: 32 taps each
        const int base = t0 + row - 4 * d;   // SAME padding: pad_lo = 4d
        int cc = cw * 32;
        int c = cc / 9, j = cc - c * 9;
#pragma unroll
        for (int m = 0; m < 4; ++m) {
            u16x8 pk;
#pragma unroll
            for (int e = 0; e < 8; ++e) {
                const int idx = base + j * d;
                float v = 0.f;
                if ((cc < CIN * KL) && idx >= 0 && idx < SEQ) v = xb[c * SEQ + idx];
                pk[e] = f2bf(v);
                ++cc;
                if (++j == KL) { j = 0; ++c; }
            }
            const int cb   = cw * 64 + m * 16;
            const int addr = row * 256 + (cb ^ ((row & 7) << 4));
            *(u16x8*)((char*)lA + addr) = pk;
        }
    }
    __syncthreads();

    // ---- A fragments -> registers ONCE (16x ds_read_b128, swizzled) ----
    const int fr = lane & 15;   // frag row (t within 16) / frag col (kernel within 16)
    const int ks = lane >> 4;   // k-slice group
    bf16x8 afrag[4][4];
#pragma unroll
    for (int m = 0; m < 4; ++m) {
        const int row = m * 16 + fr;
#pragma unroll
        for (int kk = 0; kk < 4; ++kk) {
            const int cb   = kk * 64 + ks * 16;
            const int addr = row * 256 + (cb ^ ((row & 7) << 4));
            afrag[m][kk] = *(const bf16x8*)((const char*)lA + addr);
        }
    }

    // per-lane W base: kcol(kt) = kt*64 + wv*16 + fr, k-slice ks*8 within each 32-block
    const unsigned short* wr0 = wd + (size_t)(wv * 16 + fr) * KPAD + ks * 8;

    // prefetch B tile 0
    bf16x8 bfrag[4];
#pragma unroll
    for (int kk = 0; kk < 4; ++kk)
        bfrag[kk] = *(const bf16x8*)(wr0 + kk * 32);

    for (int kt = 0; kt < NTILES; ++kt) {
        // prefetch next tile's B-frags (wraps to 0 on last iter; harmless)
        const int ktn = (kt + 1) & (NTILES - 1);
        const unsigned short* wrn = wr0 + (size_t)ktn * 64 * KPAD;
        bf16x8 bnext[4];
#pragma unroll
        for (int kk = 0; kk < 4; ++kk)
            bnext[kk] = *(const bf16x8*)(wrn + kk * 32);

        f32x4 acc[4];
#pragma unroll
        for (int m = 0; m < 4; ++m) acc[m] = (f32x4){0.f, 0.f, 0.f, 0.f};
#pragma unroll
        for (int m = 0; m < 4; ++m)
#pragma unroll
            for (int kk = 0; kk < 4; ++kk)
                acc[m] = __builtin_amdgcn_mfma_f32_16x16x32_bf16(
                    afrag[m][kk], bfrag[kk], acc[m], 0, 0, 0);

        const int kcol = kt * 64 + wv * 16 + fr;
        const float bv = (kcol < KPD) ? bb[kcol] : 3.0e38f;

        float v[16];
        unsigned pcnt = 0;
#pragma unroll
        for (int m = 0; m < 4; ++m) {
#pragma unroll
            for (int r = 0; r < 4; ++r) {
                float x = acc[m][r];
                if (TAIL) {
                    const bool ok = (t0 + m * 16 + ks * 4 + r) < SEQ;
                    x = ok ? x : -3.0e38f;
                }
                v[m * 4 + r] = x;
                pcnt += (x > bv) ? 1u : 0u;
            }
        }
        // max tree (max3-fusable)
#pragma unroll
        for (int s = 8; s >= 1; s >>= 1)
#pragma unroll
            for (int i = 0; i < s; ++i)
                v[i] = fmaxf(v[i], v[i + s]);
        float pmax = v[0];

        pmax = fmaxf(pmax, __shfl_xor(pmax, 16, 64));
        pcnt += (unsigned)__shfl_xor((int)pcnt, 16, 64);
        pmax = fmaxf(pmax, __shfl_xor(pmax, 32, 64));
        pcnt += (unsigned)__shfl_xor((int)pcnt, 32, 64);
        if (ks == 0 && kcol < KPD) {
            atomicMax(&gkey[slotbase + kcol], fkey(pmax));
            atomicAdd(&gcnt[slotbase + kcol], pcnt);
        }

#pragma unroll
        for (int kk = 0; kk < 4; ++kk) bfrag[kk] = bnext[kk];
    }
}

// grid: (79 t-chunks, ND, NB), block 256
__global__ __launch_bounds__(256, 3) void mr_main(
    const float* __restrict__ x, const unsigned short* __restrict__ wbf,
    const float* __restrict__ bias, unsigned* __restrict__ gkey,
    unsigned* __restrict__ gcnt)
{
    const int tb = blockIdx.x;
    const int di = blockIdx.y;
    const int b  = blockIdx.z;
    const int d  = 1 << di;
    const int t0 = tb * BM;

    __shared__ __align__(16) unsigned short lA[BM * KPAD];

    const float* xb = x + (size_t)b * CIN * SEQ;
    const unsigned short* wd = wbf + (size_t)di * NKP * KPAD;
    const float* bb = bias + (size_t)di * KPD;
    const size_t slotbase = ((size_t)b * ND + di) * KPD;

    if (t0 + BM <= SEQ)
        mr_body<false>(xb, wd, bb, gkey, gcnt, d, t0, lA, slotbase);
    else
        mr_body<true>(xb, wd, bb, gkey, gcnt, d, t0, lA, slotbase);
}

__global__ __launch_bounds__(256) void mr_fin(
    const unsigned* __restrict__ gkey, const unsigned* __restrict__ gcnt,
    float* __restrict__ out)
{
    const int i = blockIdx.x * 256 + threadIdx.x;   // over NB*ND*KPD
    if (i >= NB * ND * KPD) return;
    const int k  = i % KPD;
    const int di = (i / KPD) % ND;
    const int b  = i / (KPD * ND);
    const float maxv = unfkey(gkey[i]);
    const float ppv  = (float)gcnt[i] * (1.0f / (float)SEQ);
    float* ob = out + (size_t)b * (2 * ND * KPD);
    ob[di * 2 * KPD + k]       = maxv;
    ob[di * 2 * KPD + KPD + k] = ppv;
}

extern "C" void kernel_launch(void* const* d_in, const int* in_sizes, int n_in,
                              void* d_out, int out_size, void* d_ws, size_t ws_size,
                              hipStream_t stream) {
    const float* x    = (const float*)d_in[0];
    const float* w    = (const float*)d_in[1];
    const float* bias = (const float*)d_in[2];
    float* out = (float*)d_out;

    unsigned* gkey = (unsigned*)d_ws;
    unsigned* gcnt = gkey + (size_t)NB * ND * KPD;
    unsigned short* wbf = (unsigned short*)(gcnt + (size_t)NB * ND * KPD);

    hipMemsetAsync(d_ws, 0, (size_t)NB * ND * KPD * 2 * sizeof(unsigned), stream);

    const int wtot = ND * NKP * KPAD;
    wprep<<<(wtot + 255) / 256, 256, 0, stream>>>(w, wbf);

    dim3 grid((SEQ + BM - 1) / BM, ND, NB);
    mr_main<<<grid, 256, 0, stream>>>(x, wbf, bias, gkey, gcnt);

    const int tot = NB * ND * KPD;
    mr_fin<<<(tot + 255) / 256, 256, 0, stream>>>(gkey, gcnt, out);
}